// Round 1
// 253.403 us; speedup vs baseline: 1.1046x; 1.1046x over previous
//
#include <hip/hip_runtime.h>

typedef unsigned short u16;
typedef unsigned int u32;
typedef __attribute__((ext_vector_type(8))) short bf16x8;
typedef __attribute__((ext_vector_type(4))) float f32x4;
typedef __attribute__((ext_vector_type(4))) u16 u16x4;
typedef __attribute__((ext_vector_type(2))) u32 u32x2;

#define DIM 128
// Y row (2304 B): per type t in 0..3 at t*384:
//   [0,128):   q fp8 (feat = byte offset)
//   [128,384): v bf16 (feat*2)
// 1536 + t*128: k fp8 ; 2048: s bf16
#define ROWB 2304
#define QV_SPAN 384
#define K_OFF 1536
#define S_OFF 2048
#define AS1C(p) ((const __attribute__((address_space(1))) void*)(p))
#define AS3P(p) ((__attribute__((address_space(3))) void*)(p))

__device__ __forceinline__ u32 f2bf(float f){
  u32 x = __float_as_uint(f);
  return (x + 0x7fffu + ((x >> 16) & 1u)) >> 16;
}
__device__ __forceinline__ float bf2f(u16 u){
  return __uint_as_float(((u32)u) << 16);
}

// ------- prep: hist + build W (bf16,transposed,concat) + cast x->bf16 --------
// Wcat tiles (13 x 128 cols): nt<4: Wq[nt]; 4..7: Wv; 8..11: Wk; 12: mean Ws.
__global__ __launch_bounds__(256) void prep_kernel(
    const float* __restrict__ x, u16* __restrict__ xb,
    const int* __restrict__ dst, int* __restrict__ cnt, int* __restrict__ rank,
    const float* __restrict__ Wk, const float* __restrict__ bk,
    const float* __restrict__ Wq, const float* __restrict__ bq,
    const float* __restrict__ Wv, const float* __restrict__ bv,
    const float* __restrict__ Ws, const float* __restrict__ bb,
    u16* __restrict__ WcatT, float* __restrict__ biascat,
    int T, int N, int E, int rows){
  int id = blockIdx.x * 256 + threadIdx.x;
  if (id < E){                     // histogram + rank
    rank[id] = atomicAdd(&cnt[dst[id]], 1);
    return;
  }
  id -= E;
  int total_w = (3 * T + 1) * DIM * DIM;
  if (id < total_w){               // weight build
    int kk = id & (DIM - 1);
    int c  = id >> 7;
    int nt = c >> 7;
    int j  = c & (DIM - 1);
    float wv, bvv;
    if (nt < T)        { wv = Wq[(nt*DIM + kk)*DIM + j];       bvv = bq[nt*DIM + j]; }
    else if (nt < 2*T) { wv = Wv[((nt-T)*DIM + kk)*DIM + j];   bvv = bv[(nt-T)*DIM + j]; }
    else if (nt < 3*T) { wv = Wk[((nt-2*T)*DIM + kk)*DIM + j]; bvv = bk[(nt-2*T)*DIM + j]; }
    else {
      float s = 0.f, sb = 0.f;
      for (int t = 0; t < T; ++t){ s += Ws[(t*DIM + kk)*DIM + j]; sb += bb[t*DIM + j]; }
      wv = s / (float)T; bvv = sb / (float)T;
    }
    WcatT[(size_t)c * DIM + kk] = (u16)f2bf(wv);
    if (kk == 0) biascat[c] = bvv;
    return;
  }
  id -= total_w;
  int total_cast = rows * (DIM / 4);
  if (id < total_cast){            // x -> bf16 (zero-padded rows)
    int el = id * 4;
    int node = el >> 7;
    u32x2 pk;
    if (node < N){
      f32x4 v = *(const f32x4*)(x + el);
      pk.x = f2bf(v.x) | (f2bf(v.y) << 16);
      pk.y = f2bf(v.z) | (f2bf(v.w) << 16);
    } else { pk.x = 0u; pk.y = 0u; }
    *(u32x2*)(xb + el) = pk;
  }
}

// per-2048-chunk exclusive scan (offs chunk-local; bsum = chunk totals)
__global__ __launch_bounds__(256) void scan1_kernel(const int* __restrict__ cnt,
                                                    int* __restrict__ offs,
                                                    int* __restrict__ bsum, int n){
  __shared__ int wsum[4];
  const int tid = threadIdx.x;
  const int lane = tid & 63, wave = tid >> 6;
  const int base = blockIdx.x * 2048 + tid * 8;
  int v[8]; int tot = 0;
#pragma unroll
  for (int j = 0; j < 8; ++j){
    int idx = base + j;
    int val = (idx < n) ? cnt[idx] : 0;
    v[j] = val; tot += val;
  }
  int incl = tot;
#pragma unroll
  for (int d = 1; d < 64; d <<= 1){
    int u = __shfl_up(incl, d, 64);
    if (lane >= d) incl += u;
  }
  if (lane == 63) wsum[wave] = incl;
  __syncthreads();
  int wbase = 0;
#pragma unroll
  for (int w = 0; w < 4; ++w) if (w < wave) wbase += wsum[w];
  int excl = wbase + incl - tot;
  if (tid == 255) bsum[blockIdx.x] = wbase + incl;
#pragma unroll
  for (int j = 0; j < 8; ++j){
    int idx = base + j;
    if (idx < n) offs[idx] = excl;
    excl += v[j];
  }
}

// exclusive scan of chunk sums (nb <= 64)
__global__ __launch_bounds__(64) void scan2_kernel(const int* __restrict__ bsum,
                                                   int* __restrict__ boffs, int nb){
  int lane = threadIdx.x;
  int v = (lane < nb) ? bsum[lane] : 0;
  int incl = v;
#pragma unroll
  for (int d = 1; d < 64; d <<= 1){
    int u = __shfl_up(incl, d, 64);
    if (lane >= d) incl += u;
  }
  if (lane < nb) boffs[lane] = incl - v;
}

// ---------------- fused scatter + GEMM ---------------------------------------
// Blocks [0, nsc): scatter packed[] (no atomics: offs+boffs+rank).
// Blocks [nsc, ...): GEMM Y = xb @ Wcat + bias, mixed fp8/bf16 epilogue.
// W-tile (32 KB) LDS, XOR swizzle, global_load_lds w16; x frags global->VGPR.
// XCD swizzle: groups of 8 blocks = 8 m-tiles; same-mt blocks share an XCD.
// D mapping (A=W^T frag, B=x frag): col(=node)=lane&15, row(=feat)=quad*4+reg.
// Epilogue: transpose through LDS (reuse wt, dead after MFMA loop) so global
// stores are 16 B/lane over contiguous 128/256-B per-node slices (full lines),
// instead of 16 scattered 4-8 B stores per thread.
__global__ __launch_bounds__(256, 4) void gemm_scatter_kernel(
    const u16* __restrict__ xb, const u16* __restrict__ WcatT,
    const float* __restrict__ biascat, char* __restrict__ Y,
    const int* __restrict__ src, const int* __restrict__ dst,
    const int* __restrict__ et, const int* __restrict__ offs,
    const int* __restrict__ boffs, const int* __restrict__ rank,
    int* __restrict__ packed,
    int N, int E, int T, int NB, int mtiles, int nsc){
  __shared__ u16 wt[DIM * DIM];   // 32 KB (W tile, then epilogue staging)
  int bid = blockIdx.x;
  if (bid < nsc){
    int e = bid * 256 + threadIdx.x;
    if (e < E){
      int d = dst[e];
      int pos = offs[d] + boffs[d >> 11] + rank[e];
      packed[pos] = (src[e] << 2) | (et[e] & 3);
    }
    return;
  }
  bid -= nsc;
  int body = NB * (mtiles & ~7);
  int mt, nt;
  if (bid < body){
    int g = bid >> 3, r = bid & 7;
    int a = g / NB;
    mt = a * 8 + r;
    nt = g - a * NB;
  } else {
    int z = bid - body;
    mt = (mtiles & ~7) + z / NB;
    nt = z % NB;
  }
  const int m0 = mt * 128;
  const int n0 = nt * 128;
  const int tid  = threadIdx.x;
  const int wave = tid >> 6;
  const int lane = tid & 63;
  const int l15  = lane & 15;
  const int quad = lane >> 4;
  const int wrow = wave * 32;

  const u16* xrow0 = xb + (size_t)(m0 + wrow + l15) * DIM + quad * 8;
  const u16* xrow1 = xrow0 + 16 * DIM;

  // prefetch x fragments (independent of the LDS DMA)
  bf16x8 bfr[2][4];
#pragma unroll
  for (int ks = 0; ks < 4; ++ks){
    bfr[0][ks] = *(const bf16x8*)(xrow0 + ks * 32);
    bfr[1][ks] = *(const bf16x8*)(xrow1 + ks * 32);
  }

  // stage W tile, XOR swizzle: phys block p of row r holds logical p^(r&7)
#pragma unroll
  for (int it = 0; it < 8; ++it){
    int s  = it * 256 + tid;
    int r  = s >> 4;
    int p  = s & 15;
    int lb = p ^ (r & 7);
    int lbase = (it * 256 + wave * 64) * 8;
    __builtin_amdgcn_global_load_lds(AS1C(WcatT + (size_t)(n0 + r) * DIM + lb * 8),
                                     AS3P(wt + lbase), 16, 0, 0);
  }
  __syncthreads();

  f32x4 acc[2][8];
#pragma unroll
  for (int m = 0; m < 2; ++m)
#pragma unroll
    for (int f = 0; f < 8; ++f)
      acc[m][f] = (f32x4){0.f, 0.f, 0.f, 0.f};

#pragma unroll
  for (int ks = 0; ks < 4; ++ks){
    const int pb8 = (((ks * 4 + quad) ^ (l15 & 7)) * 8);
#pragma unroll
    for (int f = 0; f < 8; ++f){
      bf16x8 afr = *(const bf16x8*)&wt[(f * 16 + l15) * DIM + pb8];
      acc[0][f] = __builtin_amdgcn_mfma_f32_16x16x32_bf16(afr, bfr[0][ks], acc[0][f], 0, 0, 0);
      acc[1][f] = __builtin_amdgcn_mfma_f32_16x16x32_bf16(afr, bfr[1][ks], acc[1][f], 0, 0, 0);
    }
  }

  // ---- epilogue: LDS transpose staging (wt is dead), then wide stores -------
  // tile class: nt<T -> q fp8; [T,2T) -> v bf16; [2T,3T) -> k fp8; 3T -> s bf16
  __syncthreads();                 // all wt reads done before overwrite
  char* lds = (char*)wt;
  const bool is_q = (nt < T);
  const bool is_k = (nt >= 2*T) && (nt < 3*T);
  if (is_q || is_k){
    // fp8 slice: 128 B per node; staging 128 x 128 B = 16 KB
    const int boffb = is_q ? (nt * QV_SPAN) : (K_OFF + (nt - 2*T) * 128);
#pragma unroll
    for (int m = 0; m < 2; ++m){
      const int nl = wrow + m * 16 + l15;
#pragma unroll
      for (int f = 0; f < 8; ++f){
        const int feat = f * 16 + quad * 4;
        f32x4 b4 = *(const f32x4*)&biascat[n0 + feat];
        f32x4 v  = acc[m][f];
        u32 w = __builtin_amdgcn_cvt_pk_fp8_f32(v.x + b4.x, v.y + b4.y, 0, false);
        w = __builtin_amdgcn_cvt_pk_fp8_f32(v.z + b4.z, v.w + b4.w, w, true);
        // XOR-swizzle byte bits 4-6 with node low bits: conflict-free b32 write
        *(u32*)(lds + nl * 128 + (feat ^ ((nl & 7) << 4))) = w;
      }
    }
    __syncthreads();
    const int seg = tid & 7;       // 16-B segment within 128-B slice
    const int nr0 = tid >> 3;      // 0..31
#pragma unroll
    for (int pass = 0; pass < 4; ++pass){
      const int nl = pass * 32 + nr0;
      f32x4 d = *(const f32x4*)(lds + nl * 128 + ((seg ^ (nl & 7)) << 4));
      *(f32x4*)(Y + (size_t)(m0 + nl) * ROWB + boffb + seg * 16) = d;
    }
  } else {
    // bf16 slice: 256 B per node; staging 128 x 256 B = 32 KB
    const int boffb = (nt < 2*T) ? ((nt - T) * QV_SPAN + 128) : S_OFF;
#pragma unroll
    for (int m = 0; m < 2; ++m){
      const int nl = wrow + m * 16 + l15;
#pragma unroll
      for (int f = 0; f < 8; ++f){
        const int feat = f * 16 + quad * 4;
        f32x4 b4 = *(const f32x4*)&biascat[n0 + feat];
        f32x4 v  = acc[m][f];
        u32 lo = f2bf(v.x + b4.x) | (f2bf(v.y + b4.y) << 16);
        u32 hi = f2bf(v.z + b4.z) | (f2bf(v.w + b4.w) << 16);
        u32x2 pk = {lo, hi};
        *(u32x2*)(lds + nl * 256 + ((feat * 2) ^ ((nl & 7) << 4))) = pk;
      }
    }
    __syncthreads();
    const int seg = tid & 15;      // 16-B segment within 256-B slice
    const int nr0 = tid >> 4;      // 0..15
#pragma unroll
    for (int pass = 0; pass < 8; ++pass){
      const int nl = pass * 16 + nr0;
      f32x4 d = *(const f32x4*)(lds + nl * 256 + ((seg ^ (nl & 7)) << 4));
      *(f32x4*)(Y + (size_t)(m0 + nl) * ROWB + boffb + seg * 16) = d;
    }
  }
}

// ---------------- aggregate + epilogue: 2 nodes per wave (32 lanes each) -----
__global__ __launch_bounds__(256) void agg_kernel(const char* __restrict__ Y,
                                                  const int* __restrict__ offs,
                                                  const int* __restrict__ boffs,
                                                  const int* __restrict__ packed,
                                                  float* __restrict__ out,
                                                  int N, int E, float invT){
  const int wave = threadIdx.x >> 6;
  const int lane = threadIdx.x & 63;
  const int half = lane >> 5;
  const int l32  = lane & 31;
  const int node = blockIdx.x * 8 + wave * 2 + half;
  const bool valid = node < N;
  const int nc = valid ? node : N - 1;

  const char* yr = Y + (size_t)nc * ROWB;

  // k (fp8) per type -> f32x4; s (bf16)
  f32x4 kf[4];
#pragma unroll
  for (int t = 0; t < 4; ++t){
    u32 kw = *(const u32*)(yr + K_OFF + t * 128 + l32 * 4);
    kf[t] = (f32x4){ __builtin_amdgcn_cvt_f32_fp8(kw, 0), __builtin_amdgcn_cvt_f32_fp8(kw, 1),
                     __builtin_amdgcn_cvt_f32_fp8(kw, 2), __builtin_amdgcn_cvt_f32_fp8(kw, 3) };
  }
  u16x4 sw = *(const u16x4*)(yr + S_OFF + l32 * 8);

  int e0 = 0, e1 = 0;
  if (valid){
    e0 = offs[nc] + boffs[nc >> 11];
    e1 = (nc == N - 1) ? E : (offs[nc + 1] + boffs[(nc + 1) >> 11]);
  }

  f32x4 acc = {0.f, 0.f, 0.f, 0.f};
  int e = e0;
  for (; e + 8 <= e1; e += 8){
    int p[8];
#pragma unroll
    for (int j = 0; j < 8; ++j) p[j] = packed[e + j];
    u32 qw[8]; u16x4 vw[8];
#pragma unroll
    for (int j = 0; j < 8; ++j){
      const char* sb = Y + (size_t)(p[j] >> 2) * ROWB + (p[j] & 3) * QV_SPAN;
      qw[j] = *(const u32*)(sb + l32 * 4);
      vw[j] = *(const u16x4*)(sb + 128 + l32 * 8);
    }
#pragma unroll
    for (int j = 0; j < 8; ++j){
      int t = p[j] & 3;
      f32x4 kt = (t == 0) ? kf[0] : (t == 1) ? kf[1] : (t == 2) ? kf[2] : kf[3];
      acc.x += bf2f(vw[j].x) * __builtin_amdgcn_rcpf(1.f + __expf(-(kt.x + __builtin_amdgcn_cvt_f32_fp8(qw[j], 0))));
      acc.y += bf2f(vw[j].y) * __builtin_amdgcn_rcpf(1.f + __expf(-(kt.y + __builtin_amdgcn_cvt_f32_fp8(qw[j], 1))));
      acc.z += bf2f(vw[j].z) * __builtin_amdgcn_rcpf(1.f + __expf(-(kt.z + __builtin_amdgcn_cvt_f32_fp8(qw[j], 2))));
      acc.w += bf2f(vw[j].w) * __builtin_amdgcn_rcpf(1.f + __expf(-(kt.w + __builtin_amdgcn_cvt_f32_fp8(qw[j], 3))));
    }
  }
  for (; e < e1; ++e){
    int p = packed[e];
    int t = p & 3;
    const char* sb = Y + (size_t)(p >> 2) * ROWB + t * QV_SPAN;
    u32 qw = *(const u32*)(sb + l32 * 4);
    u16x4 vw = *(const u16x4*)(sb + 128 + l32 * 8);
    f32x4 kt = (t == 0) ? kf[0] : (t == 1) ? kf[1] : (t == 2) ? kf[2] : kf[3];
    acc.x += bf2f(vw.x) * __builtin_amdgcn_rcpf(1.f + __expf(-(kt.x + __builtin_amdgcn_cvt_f32_fp8(qw, 0))));
    acc.y += bf2f(vw.y) * __builtin_amdgcn_rcpf(1.f + __expf(-(kt.y + __builtin_amdgcn_cvt_f32_fp8(qw, 1))));
    acc.z += bf2f(vw.z) * __builtin_amdgcn_rcpf(1.f + __expf(-(kt.z + __builtin_amdgcn_cvt_f32_fp8(qw, 2))));
    acc.w += bf2f(vw.w) * __builtin_amdgcn_rcpf(1.f + __expf(-(kt.w + __builtin_amdgcn_cvt_f32_fp8(qw, 3))));
  }
  if (valid){
    f32x4 o = { invT * acc.x + bf2f(sw.x), invT * acc.y + bf2f(sw.y),
                invT * acc.z + bf2f(sw.z), invT * acc.w + bf2f(sw.w) };
    *(f32x4*)&out[(size_t)node * DIM + l32 * 4] = o;
  }
}

// ---------------- launch -----------------------------------------------------
extern "C" void kernel_launch(void* const* d_in, const int* in_sizes, int n_in,
                              void* d_out, int out_size, void* d_ws, size_t ws_size,
                              hipStream_t stream){
  const float* x  = (const float*)d_in[0];
  const int*   ei = (const int*)d_in[1];
  const int*   et = (const int*)d_in[2];
  const float* Wk = (const float*)d_in[3];
  const float* bk = (const float*)d_in[4];
  const float* Wq = (const float*)d_in[5];
  const float* bq = (const float*)d_in[6];
  const float* Wv = (const float*)d_in[7];
  const float* bv = (const float*)d_in[8];
  const float* Ws = (const float*)d_in[9];
  const float* bb = (const float*)d_in[10];
  float* out = (float*)d_out;

  const int N = in_sizes[0] / DIM;
  const int E = in_sizes[2];
  const int T = in_sizes[3] / (DIM * DIM);
  const int NB = 3 * T + 1;
  const int ncol = NB * DIM;
  const int mtiles = (N + 127) / 128;
  const int rows = mtiles * 128;
  const int nscan = (N + 2047) / 2048;
  const int nsc = (E + 255) / 256;

  char* ws = (char*)d_ws;
  size_t off = 0;
  auto alloc = [&](size_t bytes) -> char* {
    char* p = ws + off;
    off = (off + bytes + 255) & ~(size_t)255;
    return p;
  };
  u16*   xb      = (u16*)alloc((size_t)rows * DIM * 2);
  u16*   WcatT   = (u16*)alloc((size_t)ncol * DIM * 2);
  float* biascat = (float*)alloc((size_t)ncol * 4);
  char*  Y       = (char*)alloc((size_t)rows * ROWB);
  int*   cnt     = (int*)alloc((size_t)N * 4);
  int*   offs    = (int*)alloc((size_t)N * 4);
  int*   rank    = (int*)alloc((size_t)E * 4);
  int*   packed  = (int*)alloc((size_t)E * 4);
  int*   bsum    = (int*)alloc((size_t)nscan * 4);
  int*   boffs   = (int*)alloc((size_t)nscan * 4);
  (void)ws_size; (void)n_in; (void)out_size;

  const int* srcp = ei;
  const int* dstp = ei + E;

  hipMemsetAsync(cnt, 0, (size_t)N * 4, stream);
  int prep_total = E + NB * DIM * DIM + rows * (DIM / 4);
  prep_kernel<<<(prep_total + 255) / 256, 256, 0, stream>>>(
      x, xb, dstp, cnt, rank, Wk, bk, Wq, bq, Wv, bv, Ws, bb,
      WcatT, biascat, T, N, E, rows);
  scan1_kernel<<<nscan, 256, 0, stream>>>(cnt, offs, bsum, N);
  scan2_kernel<<<1, 64, 0, stream>>>(bsum, boffs, nscan);
  gemm_scatter_kernel<<<nsc + NB * mtiles, 256, 0, stream>>>(
      xb, WcatT, biascat, Y, srcp, dstp, et, offs, boffs, rank, packed,
      N, E, T, NB, mtiles, nsc);
  agg_kernel<<<(N + 7) / 8, 256, 0, stream>>>(Y, offs, boffs, packed, out, N, E, 1.0f / (float)T);
}

// Round 2
// 247.931 us; speedup vs baseline: 1.1290x; 1.0221x over previous
//
#include <hip/hip_runtime.h>

typedef unsigned short u16;
typedef unsigned int u32;
typedef __attribute__((ext_vector_type(8))) short bf16x8;
typedef __attribute__((ext_vector_type(4))) float f32x4;
typedef __attribute__((ext_vector_type(4))) u16 u16x4;
typedef __attribute__((ext_vector_type(2))) u32 u32x2;

#define DIM 128
// Y row (2304 B): per type t in 0..3 at t*384:
//   [0,128):   q fp8 (feat = byte offset)  [pre-scaled by -log2(e)]
//   [128,384): v bf16 (feat*2)
// 1536 + t*128: k fp8 [pre-scaled by -log2(e)] ; 2048: s bf16
#define ROWB 2304
#define QV_SPAN 384
#define K_OFF 1536
#define S_OFF 2048
#define AS1C(p) ((const __attribute__((address_space(1))) void*)(p))
#define AS3P(p) ((__attribute__((address_space(3))) void*)(p))

// negative log2(e): folded into Wq/bq/Wk/bk so sigmoid = rcp(1 + exp2(k'+q'))
#define QKSCALE -1.44269504088896341f

#if defined(__has_builtin)
#if __has_builtin(__builtin_amdgcn_exp2f)
#define EXP2(x) __builtin_amdgcn_exp2f(x)
#endif
#endif
#ifndef EXP2
extern "C" __device__ float __ocml_exp2_f32(float);
#define EXP2(x) __ocml_exp2_f32(x)
#endif

__device__ __forceinline__ u32 f2bf(float f){
  u32 x = __float_as_uint(f);
  return (x + 0x7fffu + ((x >> 16) & 1u)) >> 16;
}
__device__ __forceinline__ float bf2f(u16 u){
  return __uint_as_float(((u32)u) << 16);
}

// ------- prep: hist + build W (bf16,transposed,concat) + cast x->bf16 --------
// Wcat tiles (13 x 128 cols): nt<4: Wq[nt]*QKS; 4..7: Wv; 8..11: Wk*QKS; 12: mean Ws.
__global__ __launch_bounds__(256) void prep_kernel(
    const float* __restrict__ x, u16* __restrict__ xb,
    const int* __restrict__ dst, int* __restrict__ cnt, int* __restrict__ rank,
    const float* __restrict__ Wk, const float* __restrict__ bk,
    const float* __restrict__ Wq, const float* __restrict__ bq,
    const float* __restrict__ Wv, const float* __restrict__ bv,
    const float* __restrict__ Ws, const float* __restrict__ bb,
    u16* __restrict__ WcatT, float* __restrict__ biascat,
    int T, int N, int E, int rows){
  int id = blockIdx.x * 256 + threadIdx.x;
  if (id < E){                     // histogram + rank
    rank[id] = atomicAdd(&cnt[dst[id]], 1);
    return;
  }
  id -= E;
  int total_w = (3 * T + 1) * DIM * DIM;
  if (id < total_w){               // weight build
    int kk = id & (DIM - 1);
    int c  = id >> 7;
    int nt = c >> 7;
    int j  = c & (DIM - 1);
    float wv, bvv;
    if (nt < T)        { wv = Wq[(nt*DIM + kk)*DIM + j] * QKSCALE;       bvv = bq[nt*DIM + j] * QKSCALE; }
    else if (nt < 2*T) { wv = Wv[((nt-T)*DIM + kk)*DIM + j];             bvv = bv[(nt-T)*DIM + j]; }
    else if (nt < 3*T) { wv = Wk[((nt-2*T)*DIM + kk)*DIM + j] * QKSCALE; bvv = bk[(nt-2*T)*DIM + j] * QKSCALE; }
    else {
      float s = 0.f, sb = 0.f;
      for (int t = 0; t < T; ++t){ s += Ws[(t*DIM + kk)*DIM + j]; sb += bb[t*DIM + j]; }
      wv = s / (float)T; bvv = sb / (float)T;
    }
    WcatT[(size_t)c * DIM + kk] = (u16)f2bf(wv);
    if (kk == 0) biascat[c] = bvv;
    return;
  }
  id -= total_w;
  int total_cast = rows * (DIM / 4);
  if (id < total_cast){            // x -> bf16 (zero-padded rows)
    int el = id * 4;
    int node = el >> 7;
    u32x2 pk;
    if (node < N){
      f32x4 v = *(const f32x4*)(x + el);
      pk.x = f2bf(v.x) | (f2bf(v.y) << 16);
      pk.y = f2bf(v.z) | (f2bf(v.w) << 16);
    } else { pk.x = 0u; pk.y = 0u; }
    *(u32x2*)(xb + el) = pk;
  }
}

// per-2048-chunk exclusive scan (offs chunk-local; bsum = chunk totals)
__global__ __launch_bounds__(256) void scan1_kernel(const int* __restrict__ cnt,
                                                    int* __restrict__ offs,
                                                    int* __restrict__ bsum, int n){
  __shared__ int wsum[4];
  const int tid = threadIdx.x;
  const int lane = tid & 63, wave = tid >> 6;
  const int base = blockIdx.x * 2048 + tid * 8;
  int v[8]; int tot = 0;
#pragma unroll
  for (int j = 0; j < 8; ++j){
    int idx = base + j;
    int val = (idx < n) ? cnt[idx] : 0;
    v[j] = val; tot += val;
  }
  int incl = tot;
#pragma unroll
  for (int d = 1; d < 64; d <<= 1){
    int u = __shfl_up(incl, d, 64);
    if (lane >= d) incl += u;
  }
  if (lane == 63) wsum[wave] = incl;
  __syncthreads();
  int wbase = 0;
#pragma unroll
  for (int w = 0; w < 4; ++w) if (w < wave) wbase += wsum[w];
  int excl = wbase + incl - tot;
  if (tid == 255) bsum[blockIdx.x] = wbase + incl;
#pragma unroll
  for (int j = 0; j < 8; ++j){
    int idx = base + j;
    if (idx < n) offs[idx] = excl;
    excl += v[j];
  }
}

// exclusive scan of chunk sums (nb <= 64)
__global__ __launch_bounds__(64) void scan2_kernel(const int* __restrict__ bsum,
                                                   int* __restrict__ boffs, int nb){
  int lane = threadIdx.x;
  int v = (lane < nb) ? bsum[lane] : 0;
  int incl = v;
#pragma unroll
  for (int d = 1; d < 64; d <<= 1){
    int u = __shfl_up(incl, d, 64);
    if (lane >= d) incl += u;
  }
  if (lane < nb) boffs[lane] = incl - v;
}

// ---------------- fused scatter + GEMM ---------------------------------------
// Blocks [0, nsc): scatter packed[] (no atomics: offs+boffs+rank).
//   packed = src*ROWB + t*QV_SPAN (27-bit byte offset into Y) | t<<28.
// Blocks [nsc, ...): GEMM Y = xb @ Wcat + bias, mixed fp8/bf16 epilogue.
// W-tile (32 KB) LDS, XOR swizzle, global_load_lds w16; x frags global->VGPR.
// XCD swizzle: groups of 8 blocks = 8 m-tiles; same-mt blocks share an XCD.
// D mapping (A=W^T frag, B=x frag): col(=node)=lane&15, row(=feat)=quad*4+reg.
// Epilogue: transpose through LDS (reuse wt), wide 16-B/lane stores.
__global__ __launch_bounds__(256, 4) void gemm_scatter_kernel(
    const u16* __restrict__ xb, const u16* __restrict__ WcatT,
    const float* __restrict__ biascat, char* __restrict__ Y,
    const int* __restrict__ src, const int* __restrict__ dst,
    const int* __restrict__ et, const int* __restrict__ offs,
    const int* __restrict__ boffs, const int* __restrict__ rank,
    int* __restrict__ packed,
    int N, int E, int T, int NB, int mtiles, int nsc){
  __shared__ u16 wt[DIM * DIM];   // 32 KB (W tile, then epilogue staging)
  int bid = blockIdx.x;
  if (bid < nsc){
    int e = bid * 256 + threadIdx.x;
    if (e < E){
      int d = dst[e];
      int pos = offs[d] + boffs[d >> 11] + rank[e];
      int t = et[e] & 3;
      packed[pos] = src[e] * ROWB + t * QV_SPAN + (t << 28);
    }
    return;
  }
  bid -= nsc;
  int body = NB * (mtiles & ~7);
  int mt, nt;
  if (bid < body){
    int g = bid >> 3, r = bid & 7;
    int a = g / NB;
    mt = a * 8 + r;
    nt = g - a * NB;
  } else {
    int z = bid - body;
    mt = (mtiles & ~7) + z / NB;
    nt = z % NB;
  }
  const int m0 = mt * 128;
  const int n0 = nt * 128;
  const int tid  = threadIdx.x;
  const int wave = tid >> 6;
  const int lane = tid & 63;
  const int l15  = lane & 15;
  const int quad = lane >> 4;
  const int wrow = wave * 32;

  const u16* xrow0 = xb + (size_t)(m0 + wrow + l15) * DIM + quad * 8;
  const u16* xrow1 = xrow0 + 16 * DIM;

  // prefetch x fragments (independent of the LDS DMA)
  bf16x8 bfr[2][4];
#pragma unroll
  for (int ks = 0; ks < 4; ++ks){
    bfr[0][ks] = *(const bf16x8*)(xrow0 + ks * 32);
    bfr[1][ks] = *(const bf16x8*)(xrow1 + ks * 32);
  }

  // stage W tile, XOR swizzle: phys block p of row r holds logical p^(r&7)
#pragma unroll
  for (int it = 0; it < 8; ++it){
    int s  = it * 256 + tid;
    int r  = s >> 4;
    int p  = s & 15;
    int lb = p ^ (r & 7);
    int lbase = (it * 256 + wave * 64) * 8;
    __builtin_amdgcn_global_load_lds(AS1C(WcatT + (size_t)(n0 + r) * DIM + lb * 8),
                                     AS3P(wt + lbase), 16, 0, 0);
  }
  __syncthreads();

  f32x4 acc[2][8];
#pragma unroll
  for (int m = 0; m < 2; ++m)
#pragma unroll
    for (int f = 0; f < 8; ++f)
      acc[m][f] = (f32x4){0.f, 0.f, 0.f, 0.f};

#pragma unroll
  for (int ks = 0; ks < 4; ++ks){
    const int pb8 = (((ks * 4 + quad) ^ (l15 & 7)) * 8);
#pragma unroll
    for (int f = 0; f < 8; ++f){
      bf16x8 afr = *(const bf16x8*)&wt[(f * 16 + l15) * DIM + pb8];
      acc[0][f] = __builtin_amdgcn_mfma_f32_16x16x32_bf16(afr, bfr[0][ks], acc[0][f], 0, 0, 0);
      acc[1][f] = __builtin_amdgcn_mfma_f32_16x16x32_bf16(afr, bfr[1][ks], acc[1][f], 0, 0, 0);
    }
  }

  // ---- epilogue: LDS transpose staging (wt is dead), then wide stores -------
  // tile class: nt<T -> q fp8; [T,2T) -> v bf16; [2T,3T) -> k fp8; 3T -> s bf16
  __syncthreads();                 // all wt reads done before overwrite
  char* lds = (char*)wt;
  const bool is_q = (nt < T);
  const bool is_k = (nt >= 2*T) && (nt < 3*T);
  if (is_q || is_k){
    // fp8 slice: 128 B per node; staging 128 x 128 B = 16 KB
    const int boffb = is_q ? (nt * QV_SPAN) : (K_OFF + (nt - 2*T) * 128);
#pragma unroll
    for (int m = 0; m < 2; ++m){
      const int nl = wrow + m * 16 + l15;
#pragma unroll
      for (int f = 0; f < 8; ++f){
        const int feat = f * 16 + quad * 4;
        f32x4 b4 = *(const f32x4*)&biascat[n0 + feat];
        f32x4 v  = acc[m][f];
        u32 w = __builtin_amdgcn_cvt_pk_fp8_f32(v.x + b4.x, v.y + b4.y, 0, false);
        w = __builtin_amdgcn_cvt_pk_fp8_f32(v.z + b4.z, v.w + b4.w, w, true);
        // XOR-swizzle byte bits 4-6 with node low bits: conflict-free b32 write
        *(u32*)(lds + nl * 128 + (feat ^ ((nl & 7) << 4))) = w;
      }
    }
    __syncthreads();
    const int seg = tid & 7;       // 16-B segment within 128-B slice
    const int nr0 = tid >> 3;      // 0..31
#pragma unroll
    for (int pass = 0; pass < 4; ++pass){
      const int nl = pass * 32 + nr0;
      f32x4 d = *(const f32x4*)(lds + nl * 128 + ((seg ^ (nl & 7)) << 4));
      *(f32x4*)(Y + (size_t)(m0 + nl) * ROWB + boffb + seg * 16) = d;
    }
  } else {
    // bf16 slice: 256 B per node; staging 128 x 256 B = 32 KB
    const int boffb = (nt < 2*T) ? ((nt - T) * QV_SPAN + 128) : S_OFF;
#pragma unroll
    for (int m = 0; m < 2; ++m){
      const int nl = wrow + m * 16 + l15;
#pragma unroll
      for (int f = 0; f < 8; ++f){
        const int feat = f * 16 + quad * 4;
        f32x4 b4 = *(const f32x4*)&biascat[n0 + feat];
        f32x4 v  = acc[m][f];
        u32 lo = f2bf(v.x + b4.x) | (f2bf(v.y + b4.y) << 16);
        u32 hi = f2bf(v.z + b4.z) | (f2bf(v.w + b4.w) << 16);
        u32x2 pk = {lo, hi};
        *(u32x2*)(lds + nl * 256 + ((feat * 2) ^ ((nl & 7) << 4))) = pk;
      }
    }
    __syncthreads();
    const int seg = tid & 15;      // 16-B segment within 256-B slice
    const int nr0 = tid >> 4;      // 0..15
#pragma unroll
    for (int pass = 0; pass < 8; ++pass){
      const int nl = pass * 16 + nr0;
      f32x4 d = *(const f32x4*)(lds + nl * 256 + ((seg ^ (nl & 7)) << 4));
      *(f32x4*)(Y + (size_t)(m0 + nl) * ROWB + boffb + seg * 16) = d;
    }
  }
}

// ---------------- aggregate + epilogue: 2 nodes per wave (32 lanes each) -----
// packed[] holds the Y byte offset directly (27 bits) + type in bits 28-29.
// k' per type lives in LDS (per-half 2 KB table), fetched per edge with one
// ds_read_b128 instead of 12 cndmasks. Gathers: 32-bit voffset off SGPR Y base.
__global__ __launch_bounds__(256) void agg_kernel(const char* __restrict__ Y,
                                                  const int* __restrict__ offs,
                                                  const int* __restrict__ boffs,
                                                  const int* __restrict__ packed,
                                                  float* __restrict__ out,
                                                  int N, int E, float invT){
  __shared__ float klds[8 * 512];        // 8 halves x 4 types x 32 lanes x f32x4 = 16 KB
  const int wave = threadIdx.x >> 6;
  const int lane = threadIdx.x & 63;
  const int half = lane >> 5;
  const int l32  = lane & 31;
  const int hh   = wave * 2 + half;      // 0..7
  const int node = blockIdx.x * 8 + hh;
  const bool valid = node < N;
  const int nc = valid ? node : N - 1;

  const char* yr = Y + (size_t)nc * ROWB;
  char* kb = (char*)(klds + hh * 512 + l32 * 4);   // this lane's k' slot base

  // k' (fp8, pre-scaled by -log2e) per type -> LDS
#pragma unroll
  for (int t = 0; t < 4; ++t){
    u32 kw = *(const u32*)(yr + K_OFF + t * 128 + l32 * 4);
    f32x4 kt = (f32x4){ __builtin_amdgcn_cvt_f32_fp8(kw, 0), __builtin_amdgcn_cvt_f32_fp8(kw, 1),
                        __builtin_amdgcn_cvt_f32_fp8(kw, 2), __builtin_amdgcn_cvt_f32_fp8(kw, 3) };
    *(f32x4*)(kb + t * 512) = kt;
  }
  u16x4 sw = *(const u16x4*)(yr + S_OFF + l32 * 8);

  int e0 = 0, e1 = 0;
  if (valid){
    e0 = offs[nc] + boffs[nc >> 11];
    e1 = (nc == N - 1) ? E : (offs[nc + 1] + boffs[(nc + 1) >> 11]);
  }

  const u32 qoff_l = (u32)(l32 * 4);
  const u32 voff_l = (u32)(128 + l32 * 8);

  f32x4 acc = {0.f, 0.f, 0.f, 0.f};
  int e = e0;
  for (; e + 8 <= e1; e += 8){
    int p[8];
#pragma unroll
    for (int j = 0; j < 8; ++j) p[j] = packed[e + j];
    u32 qw[8]; u16x4 vw[8]; f32x4 kt[8];
#pragma unroll
    for (int j = 0; j < 8; ++j){
      u32 base = (u32)p[j] & 0x07FFFFFFu;
      qw[j] = *(const u32*)(Y + base + qoff_l);
      vw[j] = *(const u16x4*)(Y + base + voff_l);
      kt[j] = *(const f32x4*)(kb + (((u32)p[j] >> 19) & 0x600u));
    }
#pragma unroll
    for (int j = 0; j < 8; ++j){
      acc.x += bf2f(vw[j].x) * __builtin_amdgcn_rcpf(1.f + EXP2(kt[j].x + __builtin_amdgcn_cvt_f32_fp8(qw[j], 0)));
      acc.y += bf2f(vw[j].y) * __builtin_amdgcn_rcpf(1.f + EXP2(kt[j].y + __builtin_amdgcn_cvt_f32_fp8(qw[j], 1)));
      acc.z += bf2f(vw[j].z) * __builtin_amdgcn_rcpf(1.f + EXP2(kt[j].z + __builtin_amdgcn_cvt_f32_fp8(qw[j], 2)));
      acc.w += bf2f(vw[j].w) * __builtin_amdgcn_rcpf(1.f + EXP2(kt[j].w + __builtin_amdgcn_cvt_f32_fp8(qw[j], 3)));
    }
  }
  for (; e < e1; ++e){
    int p = packed[e];
    u32 base = (u32)p & 0x07FFFFFFu;
    u32 qw = *(const u32*)(Y + base + qoff_l);
    u16x4 vw = *(const u16x4*)(Y + base + voff_l);
    f32x4 kt = *(const f32x4*)(kb + (((u32)p >> 19) & 0x600u));
    acc.x += bf2f(vw.x) * __builtin_amdgcn_rcpf(1.f + EXP2(kt.x + __builtin_amdgcn_cvt_f32_fp8(qw, 0)));
    acc.y += bf2f(vw.y) * __builtin_amdgcn_rcpf(1.f + EXP2(kt.y + __builtin_amdgcn_cvt_f32_fp8(qw, 1)));
    acc.z += bf2f(vw.z) * __builtin_amdgcn_rcpf(1.f + EXP2(kt.z + __builtin_amdgcn_cvt_f32_fp8(qw, 2)));
    acc.w += bf2f(vw.w) * __builtin_amdgcn_rcpf(1.f + EXP2(kt.w + __builtin_amdgcn_cvt_f32_fp8(qw, 3)));
  }
  if (valid){
    f32x4 o = { invT * acc.x + bf2f(sw.x), invT * acc.y + bf2f(sw.y),
                invT * acc.z + bf2f(sw.z), invT * acc.w + bf2f(sw.w) };
    *(f32x4*)&out[(size_t)node * DIM + l32 * 4] = o;
  }
}

// ---------------- launch -----------------------------------------------------
extern "C" void kernel_launch(void* const* d_in, const int* in_sizes, int n_in,
                              void* d_out, int out_size, void* d_ws, size_t ws_size,
                              hipStream_t stream){
  const float* x  = (const float*)d_in[0];
  const int*   ei = (const int*)d_in[1];
  const int*   et = (const int*)d_in[2];
  const float* Wk = (const float*)d_in[3];
  const float* bk = (const float*)d_in[4];
  const float* Wq = (const float*)d_in[5];
  const float* bq = (const float*)d_in[6];
  const float* Wv = (const float*)d_in[7];
  const float* bv = (const float*)d_in[8];
  const float* Ws = (const float*)d_in[9];
  const float* bb = (const float*)d_in[10];
  float* out = (float*)d_out;

  const int N = in_sizes[0] / DIM;
  const int E = in_sizes[2];
  const int T = in_sizes[3] / (DIM * DIM);
  const int NB = 3 * T + 1;
  const int ncol = NB * DIM;
  const int mtiles = (N + 127) / 128;
  const int rows = mtiles * 128;
  const int nscan = (N + 2047) / 2048;
  const int nsc = (E + 255) / 256;

  char* ws = (char*)d_ws;
  size_t off = 0;
  auto alloc = [&](size_t bytes) -> char* {
    char* p = ws + off;
    off = (off + bytes + 255) & ~(size_t)255;
    return p;
  };
  u16*   xb      = (u16*)alloc((size_t)rows * DIM * 2);
  u16*   WcatT   = (u16*)alloc((size_t)ncol * DIM * 2);
  float* biascat = (float*)alloc((size_t)ncol * 4);
  char*  Y       = (char*)alloc((size_t)rows * ROWB);
  int*   cnt     = (int*)alloc((size_t)N * 4);
  int*   offs    = (int*)alloc((size_t)N * 4);
  int*   rank    = (int*)alloc((size_t)E * 4);
  int*   packed  = (int*)alloc((size_t)E * 4);
  int*   bsum    = (int*)alloc((size_t)nscan * 4);
  int*   boffs   = (int*)alloc((size_t)nscan * 4);
  (void)ws_size; (void)n_in; (void)out_size;

  const int* srcp = ei;
  const int* dstp = ei + E;

  hipMemsetAsync(cnt, 0, (size_t)N * 4, stream);
  int prep_total = E + NB * DIM * DIM + rows * (DIM / 4);
  prep_kernel<<<(prep_total + 255) / 256, 256, 0, stream>>>(
      x, xb, dstp, cnt, rank, Wk, bk, Wq, bq, Wv, bv, Ws, bb,
      WcatT, biascat, T, N, E, rows);
  scan1_kernel<<<nscan, 256, 0, stream>>>(cnt, offs, bsum, N);
  scan2_kernel<<<1, 64, 0, stream>>>(bsum, boffs, nscan);
  gemm_scatter_kernel<<<nsc + NB * mtiles, 256, 0, stream>>>(
      xb, WcatT, biascat, Y, srcp, dstp, et, offs, boffs, rank, packed,
      N, E, T, NB, mtiles, nsc);
  agg_kernel<<<(N + 7) / 8, 256, 0, stream>>>(Y, offs, boffs, packed, out, N, E, 1.0f / (float)T);
}